// Round 12
// baseline (196.312 us; speedup 1.0000x reference)
//
#include <hip/hip_runtime.h>
#include <cmath>

#define EMBED 1024
#define EPB   8
#define NB    64
#define KTOP  2
#define SLICE 1024          // tokens scanned per block

// ---------------------------------------------------------------------------
// Single-kernel router. Grid = NB x nslice blocks of 256 threads.
// Block (b, sl):
//   1. stages bucket b's 8 keys (32 KB) into LDS        [r11-verified body]
//   2. computes the 8 key rnorms in-block                [r3-verified FP order]
//   3. scans op[sl*SLICE .. ) for tokens with bucket==b -> LDS list (~16)
//   4. processes the list 16 tokens/pass with the r11-verified
//      4-token x 8-expert register-blocked ITER/RED/tail.
// No binning pipeline, no workspace, ONE launch: r11 accounting showed the
// 3 extra prep launches + gaps cost more than the main-kernel win, and the
// harness re-poison (~41 us fillBuffer) is the only other fixed cost.
// LDS 36.3 KB -> 4 blocks/CU resident (vs r11's 2) = 2x latency hiding on
// the gathered-h stream; 1024 blocks = one full residency round.
// ---------------------------------------------------------------------------
#define D4(a,b) ((a).x*(b).x + (a).y*(b).y + (a).z*(b).z + (a).w*(b).w)

#define ITER(i) { \
    int off = (i)*64 + lane; \
    float4 a0 = hr0[off]; float4 a1 = hr1[off]; \
    float4 a2 = hr2[off]; float4 a3 = hr3[off]; \
    float4 q0 = skv[0*256+off]; float4 q1 = skv[1*256+off]; \
    float4 q2 = skv[2*256+off]; float4 q3 = skv[3*256+off]; \
    float4 q4 = skv[4*256+off]; float4 q5 = skv[5*256+off]; \
    float4 q6 = skv[6*256+off]; float4 q7 = skv[7*256+off]; \
    hh0 += D4(a0,a0); hh1 += D4(a1,a1); hh2 += D4(a2,a2); hh3 += D4(a3,a3); \
    d00 += D4(a0,q0); d01 += D4(a0,q1); d02 += D4(a0,q2); d03 += D4(a0,q3); \
    d04 += D4(a0,q4); d05 += D4(a0,q5); d06 += D4(a0,q6); d07 += D4(a0,q7); \
    d10 += D4(a1,q0); d11 += D4(a1,q1); d12 += D4(a1,q2); d13 += D4(a1,q3); \
    d14 += D4(a1,q4); d15 += D4(a1,q5); d16 += D4(a1,q6); d17 += D4(a1,q7); \
    d20 += D4(a2,q0); d21 += D4(a2,q1); d22 += D4(a2,q2); d23 += D4(a2,q3); \
    d24 += D4(a2,q4); d25 += D4(a2,q5); d26 += D4(a2,q6); d27 += D4(a2,q7); \
    d30 += D4(a3,q0); d31 += D4(a3,q1); d32 += D4(a3,q2); d33 += D4(a3,q3); \
    d34 += D4(a3,q4); d35 += D4(a3,q5); d36 += D4(a3,q6); d37 += D4(a3,q7); }

#define RED(o) \
    hh0 += __shfl_xor(hh0,o,64); hh1 += __shfl_xor(hh1,o,64); \
    hh2 += __shfl_xor(hh2,o,64); hh3 += __shfl_xor(hh3,o,64); \
    d00 += __shfl_xor(d00,o,64); d01 += __shfl_xor(d01,o,64); \
    d02 += __shfl_xor(d02,o,64); d03 += __shfl_xor(d03,o,64); \
    d04 += __shfl_xor(d04,o,64); d05 += __shfl_xor(d05,o,64); \
    d06 += __shfl_xor(d06,o,64); d07 += __shfl_xor(d07,o,64); \
    d10 += __shfl_xor(d10,o,64); d11 += __shfl_xor(d11,o,64); \
    d12 += __shfl_xor(d12,o,64); d13 += __shfl_xor(d13,o,64); \
    d14 += __shfl_xor(d14,o,64); d15 += __shfl_xor(d15,o,64); \
    d16 += __shfl_xor(d16,o,64); d17 += __shfl_xor(d17,o,64); \
    d20 += __shfl_xor(d20,o,64); d21 += __shfl_xor(d21,o,64); \
    d22 += __shfl_xor(d22,o,64); d23 += __shfl_xor(d23,o,64); \
    d24 += __shfl_xor(d24,o,64); d25 += __shfl_xor(d25,o,64); \
    d26 += __shfl_xor(d26,o,64); d27 += __shfl_xor(d27,o,64); \
    d30 += __shfl_xor(d30,o,64); d31 += __shfl_xor(d31,o,64); \
    d32 += __shfl_xor(d32,o,64); d33 += __shfl_xor(d33,o,64); \
    d34 += __shfl_xor(d34,o,64); d35 += __shfl_xor(d35,o,64); \
    d36 += __shfl_xor(d36,o,64); d37 += __shfl_xor(d37,o,64);

#define SEL4(x0,x1,x2,x3) ((g==0)?(x0):(g==1)?(x1):(g==2)?(x2):(x3))
#define T1(e) if (ex##e > v1) { v1 = ex##e; i1 = (e); }
#define T2(e) if ((e) != i1 && ex##e > v2) { v2 = ex##e; i2 = (e); }

__global__ __launch_bounds__(256, 4) void router_mono_kernel(
    const float* __restrict__ h, const int* __restrict__ op,
    const float* __restrict__ ek,
    float* __restrict__ out_gid, float* __restrict__ out_w,
    int ntok, int nslice) {
    __shared__ float sk[EPB * EMBED];                // 32 KB
    __shared__ float s_rk[EPB];
    __shared__ int   s_list[SLICE];                  // 4 KB (worst case)
    __shared__ int   s_cnt;

    int tid  = threadIdx.x;
    int lane = tid & 63;
    int wave = tid >> 6;
    int g    = lane >> 4;                            // token group 0..3
    int r16  = lane & 15;

    int b  = blockIdx.x / nslice;                    // bucket (b-major: L2 key reuse)
    int sl = blockIdx.x - b * nslice;                // slice

    // ---- 1. stage keys: 512 coalesced float4 stores, linear ----
    const float4* src = (const float4*)ek + (size_t)b * (EPB * EMBED / 4);
    float4* dst = (float4*)sk;
#pragma unroll
    for (int j = 0; j < 8; ++j) dst[j * 256 + tid] = src[j * 256 + tid];
    if (tid == 0) s_cnt = 0;

    // ---- 2. rnorms in-block: wave w -> rows 2w,2w+1 (verified FP order) ----
#pragma unroll
    for (int rr = 0; rr < 2; ++rr) {
        int row = wave * 2 + rr;
        const float4* r4 = (const float4*)(ek + (size_t)(b * EPB + row) * EMBED);
        float s = 0.f;
#pragma unroll
        for (int c = 0; c < 4; ++c) {
            float4 v = r4[c * 64 + lane];
            s += v.x * v.x + v.y * v.y + v.z * v.z + v.w * v.w;
        }
#pragma unroll
        for (int off = 32; off; off >>= 1) s += __shfl_xor(s, off, 64);
        if (lane == 0) s_rk[row] = 1.0f / fmaxf(sqrtf(s), 1e-12f);
    }
    __syncthreads();

    // ---- 3. scan op slice, collect matching tokens into LDS list ----
    int t0 = sl * SLICE;
    int t1 = min(t0 + SLICE, ntok);
    for (int i = t0 + tid; i < t1; i += 256) {
        int ob = min(max(op[i], 0), NB - 1);
        if (ob == b) { int p = atomicAdd(&s_cnt, 1); s_list[p] = i; }
    }
    __syncthreads();
    int cnt = s_cnt;

    float rk0 = s_rk[0], rk1 = s_rk[1], rk2 = s_rk[2], rk3 = s_rk[3];
    float rk4 = s_rk[4], rk5 = s_rk[5], rk6 = s_rk[6], rk7 = s_rk[7];
    const float4* skv = (const float4*)sk;

    // ---- 4. process list: 16 tokens per pass (4/wave), r11-verified math ----
    for (int base = 0; base < cnt; base += 16) {
        int i0   = base + wave * 4;
        int tok0 = s_list[min(i0 + 0, cnt - 1)];
        int tok1 = s_list[min(i0 + 1, cnt - 1)];
        int tok2 = s_list[min(i0 + 2, cnt - 1)];
        int tok3 = s_list[min(i0 + 3, cnt - 1)];
        const float4* hr0 = (const float4*)(h + (size_t)tok0 * EMBED);
        const float4* hr1 = (const float4*)(h + (size_t)tok1 * EMBED);
        const float4* hr2 = (const float4*)(h + (size_t)tok2 * EMBED);
        const float4* hr3 = (const float4*)(h + (size_t)tok3 * EMBED);

        float hh0=0.f, hh1=0.f, hh2=0.f, hh3=0.f;
        float d00=0.f,d01=0.f,d02=0.f,d03=0.f,d04=0.f,d05=0.f,d06=0.f,d07=0.f;
        float d10=0.f,d11=0.f,d12=0.f,d13=0.f,d14=0.f,d15=0.f,d16=0.f,d17=0.f;
        float d20=0.f,d21=0.f,d22=0.f,d23=0.f,d24=0.f,d25=0.f,d26=0.f,d27=0.f;
        float d30=0.f,d31=0.f,d32=0.f,d33=0.f,d34=0.f,d35=0.f,d36=0.f,d37=0.f;

        ITER(0) ITER(1) ITER(2) ITER(3)

        RED(32) RED(16) RED(8) RED(4) RED(2) RED(1)

        // tail: 16-lane group g handles token g (uniform within group)
        float thh = SEL4(hh0, hh1, hh2, hh3);
        float t0s = SEL4(d00, d10, d20, d30);
        float t1s = SEL4(d01, d11, d21, d31);
        float t2s = SEL4(d02, d12, d22, d32);
        float t3s = SEL4(d03, d13, d23, d33);
        float t4s = SEL4(d04, d14, d24, d34);
        float t5s = SEL4(d05, d15, d25, d35);
        float t6s = SEL4(d06, d16, d26, d36);
        float t7s = SEL4(d07, d17, d27, d37);
        int   tk  = SEL4(tok0, tok1, tok2, tok3);
        int   gi  = i0 + g;

        float rh = 1.0f / fmaxf(sqrtf(thh), 1e-12f);
        float sc0 = t0s * rh * rk0, sc1 = t1s * rh * rk1;
        float sc2 = t2s * rh * rk2, sc3 = t3s * rh * rk3;
        float sc4 = t4s * rh * rk4, sc5 = t5s * rh * rk5;
        float sc6 = t6s * rh * rk6, sc7 = t7s * rh * rk7;
        float m = -1e30f;
        m = fmaxf(m, sc0); m = fmaxf(m, sc1); m = fmaxf(m, sc2); m = fmaxf(m, sc3);
        m = fmaxf(m, sc4); m = fmaxf(m, sc5); m = fmaxf(m, sc6); m = fmaxf(m, sc7);
        float ex0 = expf(sc0 - m), ex1 = expf(sc1 - m);
        float ex2 = expf(sc2 - m), ex3 = expf(sc3 - m);
        float ex4 = expf(sc4 - m), ex5 = expf(sc5 - m);
        float ex6 = expf(sc6 - m), ex7 = expf(sc7 - m);
        float Z = 0.f;
        Z += ex0; Z += ex1; Z += ex2; Z += ex3;
        Z += ex4; Z += ex5; Z += ex6; Z += ex7;
        float v1 = ex0; int i1 = 0;
        T1(1) T1(2) T1(3) T1(4) T1(5) T1(6) T1(7)
        float v2 = (i1 == 0) ? ex1 : ex0;
        int   i2 = (i1 == 0) ? 1 : 0;
        T2(0) T2(1) T2(2) T2(3) T2(4) T2(5) T2(6) T2(7)

        if (r16 == 0 && gi < cnt) {
            float p1 = v1 / Z, p2 = v2 / Z;
            float ws = p1 + p2 + 1e-9f;
            ((float2*)out_gid)[tk] =
                make_float2((float)(b * EPB + i1), (float)(b * EPB + i2));
            ((float2*)out_w)[tk] = make_float2(p1 / ws, p2 / ws);
        }
    }
}

extern "C" void kernel_launch(void* const* d_in, const int* in_sizes, int n_in,
                              void* d_out, int out_size, void* d_ws, size_t ws_size,
                              hipStream_t stream) {
    const float* h     = (const float*)d_in[0];
    const int*   op_id = (const int*)  d_in[1];
    const float* ek    = (const float*)d_in[2];

    int ntok = in_sizes[1];                          // B*T tokens

    float* out_gid = (float*)d_out;
    float* out_w   = out_gid + (size_t)ntok * KTOP;

    // Single launch: no workspace, no prep pipeline.
    int nslice = (ntok + SLICE - 1) / SLICE;
    router_mono_kernel<<<NB * nslice, 256, 0, stream>>>(
        h, op_id, ek, out_gid, out_w, ntok, nslice);
}

// Round 13
// 177.743 us; speedup vs baseline: 1.1045x; 1.1045x over previous
//
#include <hip/hip_runtime.h>
#include <cmath>

#define EMBED 1024
#define EPB   8
#define NB    64
#define KTOP  2
#define SLICE 1024          // tokens scanned per block

// ---------------------------------------------------------------------------
// Single-kernel router, spill-free edition. Grid = NB x nslice, 256 thr.
// Block (b, sl):
//   1. stage bucket b's 8 keys (32 KB) into LDS          [r11-verified]
//   2. key rnorms from the LDS copy (same values, same FP order as the
//      verified global-read body -> bitwise identical results)
//   3. scan op[sl*SLICE..) for bucket==b -> LDS token list (~16 expected)
//   4. loop: 8 tokens per block-pass, 2 tokens x 8 experts per wave.
// r12 post-mortem: the 36-accumulator body inside a runtime loop spilled to
// scratch (WRITE_SIZE 181 MB, dur 120us). This version halves the live set
// (18 accumulators + 8 key float4 + 2 h float4 ~ 70 VGPR) -- the same
// pressure class as the never-spilled r3/r4 kernels -- so the loop stays
// in registers. Cost model: total = 41(fill) + K + 11(1 launch); K<62
// beats the 114.3us session best.
// ---------------------------------------------------------------------------
#define D4(a,b) ((a).x*(b).x + (a).y*(b).y + (a).z*(b).z + (a).w*(b).w)

#define ITER2(i) { \
    int off = (i)*64 + lane; \
    float4 a0 = hr0[off]; float4 a1 = hr1[off]; \
    float4 q0 = skv[0*256+off]; float4 q1 = skv[1*256+off]; \
    float4 q2 = skv[2*256+off]; float4 q3 = skv[3*256+off]; \
    float4 q4 = skv[4*256+off]; float4 q5 = skv[5*256+off]; \
    float4 q6 = skv[6*256+off]; float4 q7 = skv[7*256+off]; \
    hh0 += D4(a0,a0); hh1 += D4(a1,a1); \
    d00 += D4(a0,q0); d01 += D4(a0,q1); d02 += D4(a0,q2); d03 += D4(a0,q3); \
    d04 += D4(a0,q4); d05 += D4(a0,q5); d06 += D4(a0,q6); d07 += D4(a0,q7); \
    d10 += D4(a1,q0); d11 += D4(a1,q1); d12 += D4(a1,q2); d13 += D4(a1,q3); \
    d14 += D4(a1,q4); d15 += D4(a1,q5); d16 += D4(a1,q6); d17 += D4(a1,q7); }

#define RED2(o) \
    hh0 += __shfl_xor(hh0,o,64); hh1 += __shfl_xor(hh1,o,64); \
    d00 += __shfl_xor(d00,o,64); d01 += __shfl_xor(d01,o,64); \
    d02 += __shfl_xor(d02,o,64); d03 += __shfl_xor(d03,o,64); \
    d04 += __shfl_xor(d04,o,64); d05 += __shfl_xor(d05,o,64); \
    d06 += __shfl_xor(d06,o,64); d07 += __shfl_xor(d07,o,64); \
    d10 += __shfl_xor(d10,o,64); d11 += __shfl_xor(d11,o,64); \
    d12 += __shfl_xor(d12,o,64); d13 += __shfl_xor(d13,o,64); \
    d14 += __shfl_xor(d14,o,64); d15 += __shfl_xor(d15,o,64); \
    d16 += __shfl_xor(d16,o,64); d17 += __shfl_xor(d17,o,64);

#define SEL2(x0,x1) ((g)?(x1):(x0))
#define T1(e) if (ex##e > v1) { v1 = ex##e; i1 = (e); }
#define T2(e) if ((e) != i1 && ex##e > v2) { v2 = ex##e; i2 = (e); }

__global__ __launch_bounds__(256, 4) void router_mono2_kernel(
    const float* __restrict__ h, const int* __restrict__ op,
    const float* __restrict__ ek,
    float* __restrict__ out_gid, float* __restrict__ out_w,
    int ntok, int nslice) {
    __shared__ float sk[EPB * EMBED];                // 32 KB
    __shared__ float s_rk[EPB];
    __shared__ int   s_list[SLICE];                  // 4 KB (worst case)
    __shared__ int   s_cnt;

    int tid  = threadIdx.x;
    int lane = tid & 63;
    int wave = tid >> 6;
    int g    = lane >> 5;                            // token half 0..1
    int r32  = lane & 31;

    int b  = blockIdx.x / nslice;                    // bucket
    int sl = blockIdx.x - b * nslice;                // slice

    // ---- 1. stage keys: 512 coalesced float4 stores, linear ----
    const float4* src = (const float4*)ek + (size_t)b * (EPB * EMBED / 4);
    float4* dst = (float4*)sk;
#pragma unroll
    for (int j = 0; j < 8; ++j) dst[j * 256 + tid] = src[j * 256 + tid];
    if (tid == 0) s_cnt = 0;
    __syncthreads();

    // ---- 2. rnorms from LDS copy (verified FP order, identical values) ----
#pragma unroll
    for (int rr = 0; rr < 2; ++rr) {
        int row = wave * 2 + rr;
        const float4* r4 = (const float4*)(sk + (size_t)row * EMBED);
        float s = 0.f;
#pragma unroll
        for (int c = 0; c < 4; ++c) {
            float4 v = r4[c * 64 + lane];
            s += v.x * v.x + v.y * v.y + v.z * v.z + v.w * v.w;
        }
#pragma unroll
        for (int off = 32; off; off >>= 1) s += __shfl_xor(s, off, 64);
        if (lane == 0) s_rk[row] = 1.0f / fmaxf(sqrtf(s), 1e-12f);
    }

    // ---- 3. scan op slice, collect matching tokens into LDS list ----
    int t0 = sl * SLICE;
    int t1 = min(t0 + SLICE, ntok);
    for (int i = t0 + tid; i < t1; i += 256) {
        int ob = min(max(op[i], 0), NB - 1);
        if (ob == b) { int p = atomicAdd(&s_cnt, 1); s_list[p] = i; }
    }
    __syncthreads();
    int cnt = s_cnt;

    float rk0 = s_rk[0], rk1 = s_rk[1], rk2 = s_rk[2], rk3 = s_rk[3];
    float rk4 = s_rk[4], rk5 = s_rk[5], rk6 = s_rk[6], rk7 = s_rk[7];
    const float4* skv = (const float4*)sk;

    // ---- 4. process list: 8 tokens per pass (2/wave), low reg pressure ----
    for (int base = 0; base < cnt; base += 8) {
        int i0   = base + wave * 2;
        int tok0 = s_list[min(i0 + 0, cnt - 1)];
        int tok1 = s_list[min(i0 + 1, cnt - 1)];
        const float4* hr0 = (const float4*)(h + (size_t)tok0 * EMBED);
        const float4* hr1 = (const float4*)(h + (size_t)tok1 * EMBED);

        float hh0=0.f, hh1=0.f;
        float d00=0.f,d01=0.f,d02=0.f,d03=0.f,d04=0.f,d05=0.f,d06=0.f,d07=0.f;
        float d10=0.f,d11=0.f,d12=0.f,d13=0.f,d14=0.f,d15=0.f,d16=0.f,d17=0.f;

        ITER2(0) ITER2(1) ITER2(2) ITER2(3)

        RED2(32) RED2(16) RED2(8) RED2(4) RED2(2) RED2(1)

        // tail: 32-lane half g handles token g (uniform within half)
        float thh = SEL2(hh0, hh1);
        float t0s = SEL2(d00, d10);
        float t1s = SEL2(d01, d11);
        float t2s = SEL2(d02, d12);
        float t3s = SEL2(d03, d13);
        float t4s = SEL2(d04, d14);
        float t5s = SEL2(d05, d15);
        float t6s = SEL2(d06, d16);
        float t7s = SEL2(d07, d17);
        int   tk  = SEL2(tok0, tok1);
        int   gi  = i0 + g;

        float rh = 1.0f / fmaxf(sqrtf(thh), 1e-12f);
        float sc0 = t0s * rh * rk0, sc1 = t1s * rh * rk1;
        float sc2 = t2s * rh * rk2, sc3 = t3s * rh * rk3;
        float sc4 = t4s * rh * rk4, sc5 = t5s * rh * rk5;
        float sc6 = t6s * rh * rk6, sc7 = t7s * rh * rk7;
        float m = -1e30f;
        m = fmaxf(m, sc0); m = fmaxf(m, sc1); m = fmaxf(m, sc2); m = fmaxf(m, sc3);
        m = fmaxf(m, sc4); m = fmaxf(m, sc5); m = fmaxf(m, sc6); m = fmaxf(m, sc7);
        float ex0 = expf(sc0 - m), ex1 = expf(sc1 - m);
        float ex2 = expf(sc2 - m), ex3 = expf(sc3 - m);
        float ex4 = expf(sc4 - m), ex5 = expf(sc5 - m);
        float ex6 = expf(sc6 - m), ex7 = expf(sc7 - m);
        float Z = 0.f;
        Z += ex0; Z += ex1; Z += ex2; Z += ex3;
        Z += ex4; Z += ex5; Z += ex6; Z += ex7;
        float v1 = ex0; int i1 = 0;
        T1(1) T1(2) T1(3) T1(4) T1(5) T1(6) T1(7)
        float v2 = (i1 == 0) ? ex1 : ex0;
        int   i2 = (i1 == 0) ? 1 : 0;
        T2(0) T2(1) T2(2) T2(3) T2(4) T2(5) T2(6) T2(7)

        if (r32 == 0 && gi < cnt) {
            float p1 = v1 / Z, p2 = v2 / Z;
            float ws = p1 + p2 + 1e-9f;
            ((float2*)out_gid)[tk] =
                make_float2((float)(b * EPB + i1), (float)(b * EPB + i2));
            ((float2*)out_w)[tk] = make_float2(p1 / ws, p2 / ws);
        }
    }
}

extern "C" void kernel_launch(void* const* d_in, const int* in_sizes, int n_in,
                              void* d_out, int out_size, void* d_ws, size_t ws_size,
                              hipStream_t stream) {
    const float* h     = (const float*)d_in[0];
    const int*   op_id = (const int*)  d_in[1];
    const float* ek    = (const float*)d_in[2];

    int ntok = in_sizes[1];                          // B*T tokens

    float* out_gid = (float*)d_out;
    float* out_w   = out_gid + (size_t)ntok * KTOP;

    // Single launch: no workspace, no prep pipeline.
    int nslice = (ntok + SLICE - 1) / SLICE;
    router_mono2_kernel<<<NB * nslice, 256, 0, stream>>>(
        h, op_id, ek, out_gid, out_w, ntok, nslice);
}

// Round 14
// 145.971 us; speedup vs baseline: 1.3449x; 1.2177x over previous
//
#include <hip/hip_runtime.h>
#include <cmath>

#define EMBED 1024
#define EPB   8
#define NB    64
#define KTOP  2

// ---------------------------------------------------------------------------
// Single-launch fused router. One wave = 2 tokens (32 lanes each); the
// r4-VERIFIED duo body (straight-line, no runtime loop -- every loop-wrapped
// variant r12/r13 spilled ~100 MB to scratch; every straight-line variant
// never spilled), extended with ON-THE-FLY key norms:
//   kk[e] += kv.kv  accumulated from the SAME register as dot[e] += a.kv
// -> zero extra memory traffic, deletes the rnorm kernel, the workspace and
// one launch+gap (cost model: total = 41us fill + kernels + ~11us/launch).
// 17 values in the 5-stage butterfly (vs 9): ~+2us DS-pipe, hidden under the
// L1-line-request wall that sets this structure's ~48us.
// ---------------------------------------------------------------------------
__global__ __launch_bounds__(256, 6) void router_fused_kernel(
    const float* __restrict__ h, const int* __restrict__ op,
    const float* __restrict__ ek,
    float* __restrict__ out_gid, float* __restrict__ out_w, int ntok) {
    int gtid = blockIdx.x * blockDim.x + threadIdx.x;
    int wid  = gtid >> 6;                      // global wave id
    int lane = threadIdx.x & 63;
    int half = lane >> 5;                      // token half 0..1
    int r    = lane & 31;                      // lane within half
    int tq   = wid * 2 + half;                 // token id
    int tc   = min(tq, ntok - 1);              // clamp (dummy = valid token)

    int b = op[tc];
    b = min(max(b, 0), NB - 1);

    const float4* hrow = (const float4*)(h + (size_t)tc * EMBED);
    const float4* kb   = (const float4*)ek + (size_t)b * (EPB * EMBED / 4);

    // ---- fused single-pass: hh, dot[e], kk[e] from one stream ----
    float dot[EPB] = {0.f, 0.f, 0.f, 0.f, 0.f, 0.f, 0.f, 0.f};
    float kk [EPB] = {0.f, 0.f, 0.f, 0.f, 0.f, 0.f, 0.f, 0.f};
    float hh = 0.f;
#pragma unroll
    for (int i = 0; i < 8; ++i) {
        float4 a = hrow[i * 32 + r];
        hh += a.x * a.x + a.y * a.y + a.z * a.z + a.w * a.w;
#pragma unroll
        for (int e = 0; e < EPB; ++e) {
            float4 kv = kb[e * 256 + i * 32 + r];
            dot[e] += a.x * kv.x + a.y * kv.y + a.z * kv.z + a.w * kv.w;
            kk [e] += kv.x * kv.x + kv.y * kv.y + kv.z * kv.z + kv.w * kv.w;
        }
    }

    // ---- 5-stage butterfly within each 32-lane half (17 values) ----
#pragma unroll
    for (int off = 16; off; off >>= 1) {
        hh += __shfl_xor(hh, off, 64);         // off<32 never leaves half
#pragma unroll
        for (int e = 0; e < EPB; ++e) {
            dot[e] += __shfl_xor(dot[e], off, 64);
            kk [e] += __shfl_xor(kk [e], off, 64);
        }
    }

    // ---- softmax + top-2, redundant on all 32 lanes (r4-verified tail) ----
    float rh = 1.0f / fmaxf(sqrtf(hh), 1e-12f);
    float sc[EPB];
    float m = -1e30f;
#pragma unroll
    for (int e = 0; e < EPB; ++e) {
        float rke = 1.0f / fmaxf(sqrtf(kk[e]), 1e-12f);
        sc[e] = dot[e] * rh * rke;             // TAU = 1.0
        m = fmaxf(m, sc[e]);
    }
    float ex[EPB];
    float Z = 0.f;
#pragma unroll
    for (int e = 0; e < EPB; ++e) { ex[e] = expf(sc[e] - m); Z += ex[e]; }

    int i1 = 0;                                 // top-1, lowest index on ties
#pragma unroll
    for (int e = 1; e < EPB; ++e) if (ex[e] > ex[i1]) i1 = e;
    int i2 = (i1 == 0) ? 1 : 0;                 // top-2 excluding i1
#pragma unroll
    for (int e = 0; e < EPB; ++e)
        if (e != i1 && ex[e] > ex[i2]) i2 = e;

    if (r == 0 && tq < ntok) {
        float p1 = ex[i1] / Z;
        float p2 = ex[i2] / Z;
        float ws = p1 + p2 + 1e-9f;
        ((float2*)out_gid)[tq] =
            make_float2((float)(b * EPB + i1), (float)(b * EPB + i2));
        ((float2*)out_w)[tq] = make_float2(p1 / ws, p2 / ws);
    }
}

extern "C" void kernel_launch(void* const* d_in, const int* in_sizes, int n_in,
                              void* d_out, int out_size, void* d_ws, size_t ws_size,
                              hipStream_t stream) {
    const float* h     = (const float*)d_in[0];
    const int*   op_id = (const int*)  d_in[1];
    const float* ek    = (const float*)d_in[2];

    int ntok = in_sizes[1];                    // B*T tokens

    float* out_gid = (float*)d_out;
    float* out_w   = out_gid + (size_t)ntok * KTOP;

    // ONE launch: 2 tokens per wave, 8 tokens per 256-thread block.
    int blocks = (ntok + 7) / 8;
    router_fused_kernel<<<blocks, 256, 0, stream>>>(h, op_id, ek,
                                                    out_gid, out_w, ntok);
}